// Round 12
// baseline (163.771 us; speedup 1.0000x reference)
//
#include <hip/hip_runtime.h>

#define N_NODES 50000
#define DIM 128
#define NH 4
#define DH 32
#define NE 800000
#define SCALEF 0.17677669529663688f   // 1/sqrt(32)

typedef _Float16 half_t;
typedef __attribute__((ext_vector_type(2))) _Float16 half2_t;
typedef __attribute__((ext_vector_type(4))) _Float16 half4_t;
typedef __attribute__((ext_vector_type(8))) _Float16 half8_t;
typedef __attribute__((ext_vector_type(4))) float f32x4;
typedef unsigned short u16;
typedef unsigned int u32;

#define NBKT 391          // buckets of 128 consecutive targets
#define EPB 4096          // edges per hist/scatter block
#define EB 196            // ceil(NE/EPB)

// ---------------- B1: weights->fp16 (blocks 0..31) + bucket histogram (blocks 32..) ----------
__global__ __launch_bounds__(256)
void prep_kernel(const float* __restrict__ w0, const float* __restrict__ w1,
                 const float* __restrict__ w2, const float* __restrict__ w3,
                 half_t* __restrict__ o0, half_t* __restrict__ o1,
                 half_t* __restrict__ o2, half_t* __restrict__ o3,
                 const int* __restrict__ tgt, int* __restrict__ gcnt)
{
    if (blockIdx.x < 32) {
        const float* src; half_t* dst;
        switch (blockIdx.x >> 3) {
            case 0: src = w0; dst = o0; break;
            case 1: src = w1; dst = o1; break;
            case 2: src = w2; dst = o2; break;
            default: src = w3; dst = o3; break;
        }
        const int i = ((blockIdx.x & 7) * 256 + threadIdx.x) * 8;   // 16384 elems per weight
        const float4 a = *(const float4*)(src + i);
        const float4 b = *(const float4*)(src + i + 4);
        half8_t o;
        o[0] = (_Float16)a.x; o[1] = (_Float16)a.y; o[2] = (_Float16)a.z; o[3] = (_Float16)a.w;
        o[4] = (_Float16)b.x; o[5] = (_Float16)b.y; o[6] = (_Float16)b.z; o[7] = (_Float16)b.w;
        *(half8_t*)(dst + i) = o;
        return;
    }
    __shared__ int cnt[512];
    const int tid = threadIdx.x;
    cnt[tid] = 0; cnt[tid + 256] = 0;
    __syncthreads();
    const int base = (blockIdx.x - 32) * EPB;
    #pragma unroll
    for (int r = 0; r < 4; ++r) {
        const int i = base + r * 1024 + tid * 4;
        if (i < NE) {
            const int4 t4 = *(const int4*)(tgt + i);
            atomicAdd(&cnt[t4.x >> 7], 1); atomicAdd(&cnt[t4.y >> 7], 1);
            atomicAdd(&cnt[t4.z >> 7], 1); atomicAdd(&cnt[t4.w >> 7], 1);
        }
    }
    __syncthreads();
    if (cnt[tid])       atomicAdd(&gcnt[tid], cnt[tid]);
    if (cnt[tid + 256]) atomicAdd(&gcnt[tid + 256], cnt[tid + 256]);
}

// ---------------- B2: scan bucket counts -> base/cursor; offs[N]=NE ----------------
__global__ __launch_bounds__(512)
void bucket_scan(const int* __restrict__ gcnt, int* __restrict__ gbase,
                 int* __restrict__ gcur, int* __restrict__ offs)
{
    __shared__ int sh[512];
    const int tid = threadIdx.x;
    const int v = gcnt[tid];
    sh[tid] = v;
    __syncthreads();
    for (int s = 1; s < 512; s <<= 1) {
        const int a = (tid >= s) ? sh[tid - s] : 0;
        __syncthreads();
        sh[tid] += a;
        __syncthreads();
    }
    const int base = sh[tid] - v;   // exclusive
    gbase[tid] = base;
    gcur[tid]  = base;
    if (tid == 0) offs[N_NODES] = NE;
}

// ---------------- B3: bucket scatter (blocks 0..EB-1) + QKV MFMA GEMM (blocks EB..) ----------
__global__ __launch_bounds__(256)
void scat_qkv(const int* __restrict__ ei,
              int* __restrict__ gcur, u32* __restrict__ BE,
              const float* __restrict__ X,
              const half_t* __restrict__ Wq, const half_t* __restrict__ Wk, const half_t* __restrict__ Wv,
              const float* __restrict__ bq, const float* __restrict__ bk, const float* __restrict__ bv,
              half_t* __restrict__ Qo, half_t* __restrict__ Ko, half_t* __restrict__ Vo)
{
    if (blockIdx.x < EB) {
        __shared__ int cnt[512];
        __shared__ int excl[512];
        __shared__ int cursor[512];
        __shared__ int goff[512];
        __shared__ u32 ebuf[EPB];
        __shared__ int stot;
        const int tid = threadIdx.x;
        cnt[tid] = 0; cnt[tid + 256] = 0;
        __syncthreads();
        const int base = blockIdx.x * EPB;
        u32 e[16];
        #pragma unroll
        for (int r = 0; r < 4; ++r) {
            const int i = base + r * 1024 + tid * 4;
            if (i < NE) {
                const int4 t4 = *(const int4*)(ei + NE + i);
                const int4 s4 = *(const int4*)(ei + i);
                e[r*4+0] = ((u32)t4.x << 16) | (u32)s4.x;
                e[r*4+1] = ((u32)t4.y << 16) | (u32)s4.y;
                e[r*4+2] = ((u32)t4.z << 16) | (u32)s4.z;
                e[r*4+3] = ((u32)t4.w << 16) | (u32)s4.w;
                atomicAdd(&cnt[t4.x >> 7], 1); atomicAdd(&cnt[t4.y >> 7], 1);
                atomicAdd(&cnt[t4.z >> 7], 1); atomicAdd(&cnt[t4.w >> 7], 1);
            } else {
                e[r*4+0] = 0xFFFFFFFFu; e[r*4+1] = 0xFFFFFFFFu;
                e[r*4+2] = 0xFFFFFFFFu; e[r*4+3] = 0xFFFFFFFFu;
            }
        }
        __syncthreads();
        excl[tid] = cnt[tid]; excl[tid + 256] = cnt[tid + 256];
        __syncthreads();
        for (int s = 1; s < 512; s <<= 1) {
            const int a0 = (tid >= s) ? excl[tid - s] : 0;
            const int a1 = excl[tid + 256 - s];
            __syncthreads();
            excl[tid] += a0; excl[tid + 256] += a1;
            __syncthreads();
        }
        const int inc0 = excl[tid], inc1 = excl[tid + 256];
        if (tid == 255) stot = inc1;
        __syncthreads();
        excl[tid] = inc0 - cnt[tid]; excl[tid + 256] = inc1 - cnt[tid + 256];
        __syncthreads();
        cursor[tid] = excl[tid]; cursor[tid + 256] = excl[tid + 256];
        __syncthreads();
        #pragma unroll
        for (int r = 0; r < 16; ++r) {
            if (e[r] != 0xFFFFFFFFu) {
                const int b = (int)(e[r] >> 16) >> 7;
                const int p = atomicAdd(&cursor[b], 1);
                ebuf[p] = e[r];
            }
        }
        __syncthreads();
        if (cnt[tid])       goff[tid]       = atomicAdd(&gcur[tid], cnt[tid]);
        if (cnt[tid + 256]) goff[tid + 256] = atomicAdd(&gcur[tid + 256], cnt[tid + 256]);
        __syncthreads();
        const int total = stot;
        for (int k = tid; k < total; k += 256) {
            const u32 ev = ebuf[k];
            const int b = (int)(ev >> 16) >> 7;
            BE[goff[b] + (k - excl[b])] = ev;
        }
        return;
    }

    const int bid  = blockIdx.x - EB;
    const int lane = threadIdx.x & 63;
    const int wv   = threadIdx.x >> 6;
    const int m0   = bid * 128 + wv * 32;
    const int cl   = lane & 15;           // node within group / W row within tile
    const int kg   = lane >> 4;           // k-slice

    half8_t bx[2][4];
    #pragma unroll
    for (int ng = 0; ng < 2; ++ng) {
        const int row = m0 + ng * 16 + cl;
        #pragma unroll
        for (int ks = 0; ks < 4; ++ks) {
            if (row < N_NODES) {
                const float* xp = X + (size_t)row * DIM + ks * 32 + kg * 8;
                const float4 x0 = *(const float4*)(xp);
                const float4 x1 = *(const float4*)(xp + 4);
                half8_t c;
                c[0] = (_Float16)x0.x; c[1] = (_Float16)x0.y; c[2] = (_Float16)x0.z; c[3] = (_Float16)x0.w;
                c[4] = (_Float16)x1.x; c[5] = (_Float16)x1.y; c[6] = (_Float16)x1.z; c[7] = (_Float16)x1.w;
                bx[ng][ks] = c;
            } else {
                bx[ng][ks] = (half8_t)(_Float16)0.0f;
            }
        }
    }

    const half_t* Ws[3] = {Wq, Wk, Wv};
    const float*  Bs[3] = {bq, bk, bv};
    half_t*       Os[3] = {Qo, Ko, Vo};

    #pragma unroll
    for (int o = 0; o < 3; ++o) {
        const half_t* W = Ws[o];
        half_t* O = Os[o];
        #pragma unroll
        for (int ct = 0; ct < 8; ++ct) {
            f32x4 acc0 = {0.f, 0.f, 0.f, 0.f};
            f32x4 acc1 = {0.f, 0.f, 0.f, 0.f};
            #pragma unroll
            for (int ks = 0; ks < 4; ++ks) {
                const half8_t a = *(const half8_t*)(W + (size_t)(ct * 16 + cl) * DIM + ks * 32 + kg * 8);
                acc0 = __builtin_amdgcn_mfma_f32_16x16x32_f16(a, bx[0][ks], acc0, 0, 0, 0);
                acc1 = __builtin_amdgcn_mfma_f32_16x16x32_f16(a, bx[1][ks], acc1, 0, 0, 0);
            }
            const int c0 = ct * 16 + kg * 4;            // this lane's 4 consecutive outcols
            const float4 b4 = *(const float4*)(Bs[o] + c0);
            const int n0 = m0 + cl;
            if (n0 < N_NODES) {
                half4_t hd4;
                hd4[0] = (_Float16)(acc0[0] + b4.x); hd4[1] = (_Float16)(acc0[1] + b4.y);
                hd4[2] = (_Float16)(acc0[2] + b4.z); hd4[3] = (_Float16)(acc0[3] + b4.w);
                *(half4_t*)(O + (size_t)n0 * DIM + c0) = hd4;
            }
            const int n1 = m0 + 16 + cl;
            if (n1 < N_NODES) {
                half4_t hd4;
                hd4[0] = (_Float16)(acc1[0] + b4.x); hd4[1] = (_Float16)(acc1[1] + b4.y);
                hd4[2] = (_Float16)(acc1[2] + b4.z); hd4[3] = (_Float16)(acc1[3] + b4.w);
                *(half4_t*)(O + (size_t)n1 * DIM + c0) = hd4;
            }
        }
    }
}

// ---------------- B4: per-bucket CSR finalize: offs + srcs (LDS atomics only) ----------------
__global__ __launch_bounds__(256)
void csr_build(const u32* __restrict__ BE, const int* __restrict__ gbase,
               int* __restrict__ offs, int* __restrict__ srcs)
{
    __shared__ int dcnt[128], dof[128], dcur[128];
    const int b   = blockIdx.x;
    const int tid = threadIdx.x;
    const int t0  = b << 7;
    const int nt  = (N_NODES - t0) < 128 ? (N_NODES - t0) : 128;
    const int base = gbase[b];
    const int end  = gbase[b + 1];
    if (tid < 128) dcnt[tid] = 0;
    __syncthreads();
    for (int k = base + tid; k < end; k += 256)
        atomicAdd(&dcnt[(int)(BE[k] >> 16) - t0], 1);
    __syncthreads();
    if (tid < 128) dof[tid] = dcnt[tid];
    __syncthreads();
    for (int s = 1; s < 128; s <<= 1) {
        int a = 0;
        if (tid < 128 && tid >= s) a = dof[tid - s];
        __syncthreads();
        if (tid < 128) dof[tid] += a;
        __syncthreads();
    }
    if (tid < 128) {
        const int ex = dof[tid] - dcnt[tid];
        dof[tid] = ex;
        dcur[tid] = 0;
        if (tid < nt) offs[t0 + tid] = base + ex;
    }
    __syncthreads();
    for (int k = base + tid; k < end; k += 256) {
        const u32 ev = BE[k];
        const int tl = (int)(ev >> 16) - t0;
        const int p  = atomicAdd(&dcur[tl], 1);
        srcs[base + dof[tl] + p] = (int)(ev & 0xFFFFu);
    }
}

// ---------------- output GEMM + bias + residual + LayerNorm, transposed output ----------------
__global__ __launch_bounds__(256)
void out_mfma_ln(const half_t* __restrict__ Ah, const half_t* __restrict__ Wo,
                 const float* __restrict__ bo, const float* __restrict__ X,
                 const float* __restrict__ lng, const float* __restrict__ lnb,
                 float* __restrict__ out)
{
    const int lane = threadIdx.x & 63;
    const int wv   = threadIdx.x >> 6;
    const int m0   = blockIdx.x * 128 + wv * 32;
    const int cl   = lane & 15;
    const int kg   = lane >> 4;

    half8_t bx[2][4];
    #pragma unroll
    for (int ng = 0; ng < 2; ++ng) {
        const int row = m0 + ng * 16 + cl;
        #pragma unroll
        for (int ks = 0; ks < 4; ++ks) {
            if (row < N_NODES)
                bx[ng][ks] = *(const half8_t*)(Ah + (size_t)row * DIM + ks * 32 + kg * 8);
            else
                bx[ng][ks] = (half8_t)(_Float16)0.0f;
        }
    }

    float y[2][8][4];
    #pragma unroll
    for (int ct = 0; ct < 8; ++ct) {
        f32x4 acc0 = {0.f, 0.f, 0.f, 0.f};
        f32x4 acc1 = {0.f, 0.f, 0.f, 0.f};
        #pragma unroll
        for (int ks = 0; ks < 4; ++ks) {
            const half8_t a = *(const half8_t*)(Wo + (size_t)(ct * 16 + cl) * DIM + ks * 32 + kg * 8);
            acc0 = __builtin_amdgcn_mfma_f32_16x16x32_f16(a, bx[0][ks], acc0, 0, 0, 0);
            acc1 = __builtin_amdgcn_mfma_f32_16x16x32_f16(a, bx[1][ks], acc1, 0, 0, 0);
        }
        const int c0 = ct * 16 + kg * 4;
        const float4 b4 = *(const float4*)(bo + c0);
        const int n0 = m0 + cl;
        const int n1 = m0 + 16 + cl;
        float4 x0 = make_float4(0.f, 0.f, 0.f, 0.f), x1 = x0;
        if (n0 < N_NODES) x0 = *(const float4*)(X + (size_t)n0 * DIM + c0);
        if (n1 < N_NODES) x1 = *(const float4*)(X + (size_t)n1 * DIM + c0);
        y[0][ct][0] = acc0[0] + b4.x + x0.x; y[0][ct][1] = acc0[1] + b4.y + x0.y;
        y[0][ct][2] = acc0[2] + b4.z + x0.z; y[0][ct][3] = acc0[3] + b4.w + x0.w;
        y[1][ct][0] = acc1[0] + b4.x + x1.x; y[1][ct][1] = acc1[1] + b4.y + x1.y;
        y[1][ct][2] = acc1[2] + b4.z + x1.z; y[1][ct][3] = acc1[3] + b4.w + x1.w;
    }

    #pragma unroll
    for (int ng = 0; ng < 2; ++ng) {
        float s = 0.f, sq = 0.f;
        #pragma unroll
        for (int ct = 0; ct < 8; ++ct)
            #pragma unroll
            for (int j = 0; j < 4; ++j) { const float v = y[ng][ct][j]; s += v; sq += v * v; }
        s += __shfl_xor(s, 16); sq += __shfl_xor(sq, 16);
        s += __shfl_xor(s, 32); sq += __shfl_xor(sq, 32);
        const float mu   = s * (1.0f / 128.0f);
        const float var  = sq * (1.0f / 128.0f) - mu * mu;
        const float rstd = rsqrtf(var + 1e-5f);
        const int node = m0 + ng * 16 + cl;
        if (node < N_NODES) {
            #pragma unroll
            for (int ct = 0; ct < 8; ++ct) {
                const int c0 = ct * 16 + kg * 4;
                const float4 g4 = *(const float4*)(lng + c0);
                const float4 l4 = *(const float4*)(lnb + c0);
                float4 ov;
                ov.x = g4.x * (y[ng][ct][0] - mu) * rstd + l4.x;
                ov.y = g4.y * (y[ng][ct][1] - mu) * rstd + l4.y;
                ov.z = g4.z * (y[ng][ct][2] - mu) * rstd + l4.z;
                ov.w = g4.w * (y[ng][ct][3] - mu) * rstd + l4.w;
                *(float4*)(out + (size_t)node * DIM + c0) = ov;
            }
        }
    }
}

// ---------------- per-node attention + aggregation: TWO nodes per wave (ILP) ----------------
// Per node: score layout lane = 4*jl + h; V layout lane owns dims d16*8..+7 (16B loads,
// 4 passes x 4 edges). Both nodes' chunk loops interleaved -> ~2x outstanding misses/wave.
// All per-node arrays statically indexed (#pragma unroll) to stay in registers.
__global__ __launch_bounds__(256)
void attn_agg(const half_t* __restrict__ Qh, const half_t* __restrict__ Kh,
              const half_t* __restrict__ Vh, const int* __restrict__ offs,
              const int* __restrict__ srcs, half_t* __restrict__ AGG)
{
    const int lane  = threadIdx.x & 63;
    const int wv    = threadIdx.x >> 6;
    const int tbase = blockIdx.x * 8 + wv * 2;
    if (tbase >= N_NODES) return;
    const int h   = lane & 3;
    const int jl  = lane >> 2;
    const int d16 = lane & 15;
    const int hv  = d16 >> 2;
    const int jv  = lane >> 4;

    int off[2], deg[2], nch[2];
    #pragma unroll
    for (int n = 0; n < 2; ++n) {
        const int t = tbase + n;
        if (t < N_NODES) { off[n] = offs[t]; deg[n] = offs[t + 1] - off[n]; }
        else             { off[n] = 0;       deg[n] = 0; }
        nch[n] = (deg[n] + 15) >> 4;
    }
    const int nmax = nch[0] > nch[1] ? nch[0] : nch[1];

    half2_t q2[2][16];
    #pragma unroll
    for (int n = 0; n < 2; ++n) {
        const int t = tbase + n;
        if (t < N_NODES) {
            const half_t* qp = Qh + (size_t)t * DIM + h * DH;
            #pragma unroll
            for (int i = 0; i < 4; ++i) {
                union { half8_t v8; half2_t v2[4]; } u;
                u.v8 = *(const half8_t*)(qp + i * 8);
                #pragma unroll
                for (int p = 0; p < 4; ++p) q2[n][i * 4 + p] = u.v2[p];
            }
        } else {
            #pragma unroll
            for (int p = 0; p < 16; ++p) q2[n][p] = (half2_t)(_Float16)0.0f;
        }
    }

    float ssumL[2] = {0.f, 0.f};
    half2_t acc[2][4];
    #pragma unroll
    for (int n = 0; n < 2; ++n)
        #pragma unroll
        for (int q = 0; q < 4; ++q) acc[n][q] = (half2_t)(_Float16)0.0f;

    int sA[2] = {0, 0};
    half2_t kA[2][16] = {};
    #pragma unroll
    for (int n = 0; n < 2; ++n) {
        const int cnt0 = deg[n] < 16 ? deg[n] : 16;
        if (jl < cnt0) {
            sA[n] = srcs[off[n] + jl];
            const half_t* kp = Kh + (size_t)sA[n] * DIM + h * DH;
            #pragma unroll
            for (int i = 0; i < 4; ++i) {
                union { half8_t v8; half2_t v2[4]; } u;
                u.v8 = *(const half8_t*)(kp + i * 8);
                #pragma unroll
                for (int p = 0; p < 4; ++p) kA[n][i * 4 + p] = u.v2[p];
            }
        }
    }

    for (int c = 0; c < nmax; ++c) {
        const int base = c << 4;

        // prefetch next chunk's srcs + K for both nodes (independent streams)
        int sB[2] = {0, 0};
        half2_t kB[2][16] = {};
        #pragma unroll
        for (int n = 0; n < 2; ++n) {
            if (c + 1 < nch[n]) {
                const int rem = deg[n] - base - 16;
                const int cntn = rem < 16 ? rem : 16;
                if (jl < cntn) {
                    sB[n] = srcs[off[n] + base + 16 + jl];
                    const half_t* kp = Kh + (size_t)sB[n] * DIM + h * DH;
                    #pragma unroll
                    for (int i = 0; i < 4; ++i) {
                        union { half8_t v8; half2_t v2[4]; } u;
                        u.v8 = *(const half8_t*)(kp + i * 8);
                        #pragma unroll
                        for (int p = 0; p < 4; ++p) kB[n][i * 4 + p] = u.v2[p];
                    }
                }
            }
        }

        // scores + V aggregation, both nodes (independent -> scheduler overlaps)
        #pragma unroll
        for (int n = 0; n < 2; ++n) {
            if (c < nch[n]) {
                const int cnt = (deg[n] - base) < 16 ? (deg[n] - base) : 16;
                float dq = 0.f;
                #pragma unroll
                for (int p = 0; p < 16; ++p)
                    dq = __builtin_amdgcn_fdot2(kA[n][p], q2[n][p], dq, false);
                const float e = (jl < cnt) ? __expf(dq * SCALEF) : 0.f;
                ssumL[n] += e;

                union { u32 u; half2_t h2; } pe;
                const _Float16 eh = (_Float16)e;
                pe.h2[0] = eh; pe.h2[1] = eh;
                const int peI = (int)pe.u;

                #pragma unroll
                for (int p = 0; p < 4; ++p) {
                    const int j  = p * 4 + jv;
                    const int sj = __shfl(sA[n], j * 4);
                    union { u32 u; half2_t h2; } e2;
                    e2.u = (u32)__shfl(peI, j * 4 + hv);
                    union { half8_t v8; half2_t h2[4]; } v;
                    v.v8 = *(const half8_t*)(Vh + (size_t)sj * DIM + d16 * 8);
                    acc[n][0] = e2.h2 * v.h2[0] + acc[n][0];
                    acc[n][1] = e2.h2 * v.h2[1] + acc[n][1];
                    acc[n][2] = e2.h2 * v.h2[2] + acc[n][2];
                    acc[n][3] = e2.h2 * v.h2[3] + acc[n][3];
                }
            }
        }

        #pragma unroll
        for (int n = 0; n < 2; ++n) {
            sA[n] = sB[n];
            #pragma unroll
            for (int p = 0; p < 16; ++p) kA[n][p] = kB[n][p];
        }
    }

    // epilogue per node: combine edge groups, normalize, store
    #pragma unroll
    for (int n = 0; n < 2; ++n) {
        const int t = tbase + n;
        if (t >= N_NODES) continue;
        half2_t a[4];
        #pragma unroll
        for (int q = 0; q < 4; ++q) {
            union { u32 u; half2_t h2; } cq, dq16, dq32;
            cq.h2 = acc[n][q];
            dq16.u = (u32)__shfl_xor((int)cq.u, 16);
            cq.h2 = cq.h2 + dq16.h2;
            dq32.u = (u32)__shfl_xor((int)cq.u, 32);
            a[q] = cq.h2 + dq32.h2;
        }
        float se = ssumL[n];
        #pragma unroll
        for (int ww = 4; ww < 64; ww <<= 1) se += __shfl_xor(se, ww);
        const float sh = __shfl(se, hv);
        const float inv = 1.0f / (sh + 1e-10f);
        if (lane < 16) {
            half8_t o;
            #pragma unroll
            for (int q = 0; q < 4; ++q) {
                o[2*q]   = (_Float16)((float)a[q][0] * inv);
                o[2*q+1] = (_Float16)((float)a[q][1] * inv);
            }
            *(half8_t*)(AGG + (size_t)t * DIM + d16 * 8) = o;
        }
    }
}

extern "C" void kernel_launch(void* const* d_in, const int* in_sizes, int n_in,
                              void* d_out, int out_size, void* d_ws, size_t ws_size,
                              hipStream_t stream)
{
    const float* X   = (const float*)d_in[0];
    const float* Wq  = (const float*)d_in[1];
    const float* bq  = (const float*)d_in[2];
    const float* Wk  = (const float*)d_in[3];
    const float* bk  = (const float*)d_in[4];
    const float* Wv  = (const float*)d_in[5];
    const float* bv  = (const float*)d_in[6];
    const float* Wo  = (const float*)d_in[7];
    const float* bo  = (const float*)d_in[8];
    const float* lng = (const float*)d_in[9];
    const float* lnb = (const float*)d_in[10];
    const int*   ei  = (const int*)d_in[11];
    float* out = (float*)d_out;

    const size_t ND = (size_t)N_NODES * DIM;   // 6.4M elems
    half_t* Qh   = (half_t*)d_ws;
    half_t* Kh   = Qh + ND;
    half_t* Vh   = Kh + ND;
    half_t* AGGh = Vh + ND;
    half_t* Wqh  = AGGh + ND;
    half_t* Wkh  = Wqh + DIM * DIM;
    half_t* Wvh  = Wkh + DIM * DIM;
    half_t* Woh  = Wvh + DIM * DIM;
    u32* BE   = (u32*)(Woh + DIM * DIM);
    int* OFFS = (int*)(BE + NE);
    int* SRCS = OFFS + N_NODES + 1;
    int* GCNT = SRCS + NE;
    int* GBASE = GCNT + 512;
    int* GCUR  = GBASE + 512;

    hipMemsetAsync(GCNT, 0, 512 * sizeof(int), stream);

    // weights -> fp16 + bucket histogram (one launch)
    prep_kernel<<<32 + EB, 256, 0, stream>>>(Wq, Wk, Wv, Wo, Wqh, Wkh, Wvh, Woh,
                                             ei + NE, GCNT);

    // bucket scan -> base/cursor
    bucket_scan<<<1, 512, 0, stream>>>(GCNT, GBASE, GCUR, OFFS);

    // bucket scatter + QKV projections (one launch; independent block ranges)
    const int gemmGrid = (N_NODES + 127) / 128;   // 391
    scat_qkv<<<EB + gemmGrid, 256, 0, stream>>>(ei, GCUR, BE,
                                                X, Wqh, Wkh, Wvh, bq, bk, bv,
                                                Qh, Kh, Vh);

    // per-bucket CSR finalize (LDS atomics only)
    csr_build<<<NBKT, 256, 0, stream>>>(BE, GBASE, OFFS, SRCS);

    // attention + aggregation (2 nodes/wave)
    attn_agg<<<(N_NODES + 7) / 8, 256, 0, stream>>>(Qh, Kh, Vh, OFFS, SRCS, AGGh);

    // output projection + residual + LayerNorm
    out_mfma_ln<<<gemmGrid, 256, 0, stream>>>(AGGh, Woh, bo, X, lng, lnb, out);
}

// Round 13
// 147.152 us; speedup vs baseline: 1.1129x; 1.1129x over previous
//
#include <hip/hip_runtime.h>

#define N_NODES 50000
#define DIM 128
#define NH 4
#define DH 32
#define NE 800000
#define SCALEF 0.17677669529663688f   // 1/sqrt(32)

typedef _Float16 half_t;
typedef __attribute__((ext_vector_type(2))) _Float16 half2_t;
typedef __attribute__((ext_vector_type(4))) _Float16 half4_t;
typedef __attribute__((ext_vector_type(8))) _Float16 half8_t;
typedef __attribute__((ext_vector_type(4))) float f32x4;
typedef __attribute__((ext_vector_type(2))) float f32x2;
typedef unsigned short u16;
typedef unsigned int u32;
typedef unsigned char u8;

#define NBKT 391          // buckets of 128 consecutive targets
#define EPB 4096          // edges per hist/scatter block
#define EB 196            // ceil(NE/EPB)

// ---------------- B1: weights->fp16 (blocks 0..31) + bucket histogram (blocks 32..) ----------
__global__ __launch_bounds__(256)
void prep_kernel(const float* __restrict__ w0, const float* __restrict__ w1,
                 const float* __restrict__ w2, const float* __restrict__ w3,
                 half_t* __restrict__ o0, half_t* __restrict__ o1,
                 half_t* __restrict__ o2, half_t* __restrict__ o3,
                 const int* __restrict__ tgt, int* __restrict__ gcnt)
{
    if (blockIdx.x < 32) {
        const float* src; half_t* dst;
        switch (blockIdx.x >> 3) {
            case 0: src = w0; dst = o0; break;
            case 1: src = w1; dst = o1; break;
            case 2: src = w2; dst = o2; break;
            default: src = w3; dst = o3; break;
        }
        const int i = ((blockIdx.x & 7) * 256 + threadIdx.x) * 8;   // 16384 elems per weight
        const float4 a = *(const float4*)(src + i);
        const float4 b = *(const float4*)(src + i + 4);
        half8_t o;
        o[0] = (_Float16)a.x; o[1] = (_Float16)a.y; o[2] = (_Float16)a.z; o[3] = (_Float16)a.w;
        o[4] = (_Float16)b.x; o[5] = (_Float16)b.y; o[6] = (_Float16)b.z; o[7] = (_Float16)b.w;
        *(half8_t*)(dst + i) = o;
        return;
    }
    __shared__ int cnt[512];
    const int tid = threadIdx.x;
    cnt[tid] = 0; cnt[tid + 256] = 0;
    __syncthreads();
    const int base = (blockIdx.x - 32) * EPB;
    #pragma unroll
    for (int r = 0; r < 4; ++r) {
        const int i = base + r * 1024 + tid * 4;
        if (i < NE) {
            const int4 t4 = *(const int4*)(tgt + i);
            atomicAdd(&cnt[t4.x >> 7], 1); atomicAdd(&cnt[t4.y >> 7], 1);
            atomicAdd(&cnt[t4.z >> 7], 1); atomicAdd(&cnt[t4.w >> 7], 1);
        }
    }
    __syncthreads();
    if (cnt[tid])       atomicAdd(&gcnt[tid], cnt[tid]);
    if (cnt[tid + 256]) atomicAdd(&gcnt[tid + 256], cnt[tid + 256]);
}

// ---------------- B2: scan bucket counts -> base/cursor; offs[N]=NE ----------------
__global__ __launch_bounds__(512)
void bucket_scan(const int* __restrict__ gcnt, int* __restrict__ gbase,
                 int* __restrict__ gcur, int* __restrict__ offs)
{
    __shared__ int sh[512];
    const int tid = threadIdx.x;
    const int v = gcnt[tid];
    sh[tid] = v;
    __syncthreads();
    for (int s = 1; s < 512; s <<= 1) {
        const int a = (tid >= s) ? sh[tid - s] : 0;
        __syncthreads();
        sh[tid] += a;
        __syncthreads();
    }
    const int base = sh[tid] - v;   // exclusive
    gbase[tid] = base;
    gcur[tid]  = base;
    if (tid == 0) offs[N_NODES] = NE;
}

// ---------------- B3: bucket scatter (blocks 0..EB-1) + QKV MFMA GEMM (blocks EB..) ----------
// GEMM outputs: Q/V -> fp16, K -> fp8 e4m3 (cuts attn K-gather traffic in half).
__global__ __launch_bounds__(256)
void scat_qkv(const int* __restrict__ ei,
              int* __restrict__ gcur, u32* __restrict__ BE,
              const float* __restrict__ X,
              const half_t* __restrict__ Wq, const half_t* __restrict__ Wk, const half_t* __restrict__ Wv,
              const float* __restrict__ bq, const float* __restrict__ bk, const float* __restrict__ bv,
              half_t* __restrict__ Qo, u8* __restrict__ K8, half_t* __restrict__ Vo)
{
    if (blockIdx.x < EB) {
        __shared__ int cnt[512];
        __shared__ int excl[512];
        __shared__ int cursor[512];
        __shared__ int goff[512];
        __shared__ u32 ebuf[EPB];
        __shared__ int stot;
        const int tid = threadIdx.x;
        cnt[tid] = 0; cnt[tid + 256] = 0;
        __syncthreads();
        const int base = blockIdx.x * EPB;
        u32 e[16];
        #pragma unroll
        for (int r = 0; r < 4; ++r) {
            const int i = base + r * 1024 + tid * 4;
            if (i < NE) {
                const int4 t4 = *(const int4*)(ei + NE + i);
                const int4 s4 = *(const int4*)(ei + i);
                e[r*4+0] = ((u32)t4.x << 16) | (u32)s4.x;
                e[r*4+1] = ((u32)t4.y << 16) | (u32)s4.y;
                e[r*4+2] = ((u32)t4.z << 16) | (u32)s4.z;
                e[r*4+3] = ((u32)t4.w << 16) | (u32)s4.w;
                atomicAdd(&cnt[t4.x >> 7], 1); atomicAdd(&cnt[t4.y >> 7], 1);
                atomicAdd(&cnt[t4.z >> 7], 1); atomicAdd(&cnt[t4.w >> 7], 1);
            } else {
                e[r*4+0] = 0xFFFFFFFFu; e[r*4+1] = 0xFFFFFFFFu;
                e[r*4+2] = 0xFFFFFFFFu; e[r*4+3] = 0xFFFFFFFFu;
            }
        }
        __syncthreads();
        excl[tid] = cnt[tid]; excl[tid + 256] = cnt[tid + 256];
        __syncthreads();
        for (int s = 1; s < 512; s <<= 1) {
            const int a0 = (tid >= s) ? excl[tid - s] : 0;
            const int a1 = excl[tid + 256 - s];
            __syncthreads();
            excl[tid] += a0; excl[tid + 256] += a1;
            __syncthreads();
        }
        const int inc0 = excl[tid], inc1 = excl[tid + 256];
        if (tid == 255) stot = inc1;
        __syncthreads();
        excl[tid] = inc0 - cnt[tid]; excl[tid + 256] = inc1 - cnt[tid + 256];
        __syncthreads();
        cursor[tid] = excl[tid]; cursor[tid + 256] = excl[tid + 256];
        __syncthreads();
        #pragma unroll
        for (int r = 0; r < 16; ++r) {
            if (e[r] != 0xFFFFFFFFu) {
                const int b = (int)(e[r] >> 16) >> 7;
                const int p = atomicAdd(&cursor[b], 1);
                ebuf[p] = e[r];
            }
        }
        __syncthreads();
        if (cnt[tid])       goff[tid]       = atomicAdd(&gcur[tid], cnt[tid]);
        if (cnt[tid + 256]) goff[tid + 256] = atomicAdd(&gcur[tid + 256], cnt[tid + 256]);
        __syncthreads();
        const int total = stot;
        for (int k = tid; k < total; k += 256) {
            const u32 ev = ebuf[k];
            const int b = (int)(ev >> 16) >> 7;
            BE[goff[b] + (k - excl[b])] = ev;
        }
        return;
    }

    const int bid  = blockIdx.x - EB;
    const int lane = threadIdx.x & 63;
    const int wv   = threadIdx.x >> 6;
    const int m0   = bid * 128 + wv * 32;
    const int cl   = lane & 15;           // node within group / W row within tile
    const int kg   = lane >> 4;           // k-slice

    half8_t bx[2][4];
    #pragma unroll
    for (int ng = 0; ng < 2; ++ng) {
        const int row = m0 + ng * 16 + cl;
        #pragma unroll
        for (int ks = 0; ks < 4; ++ks) {
            if (row < N_NODES) {
                const float* xp = X + (size_t)row * DIM + ks * 32 + kg * 8;
                const float4 x0 = *(const float4*)(xp);
                const float4 x1 = *(const float4*)(xp + 4);
                half8_t c;
                c[0] = (_Float16)x0.x; c[1] = (_Float16)x0.y; c[2] = (_Float16)x0.z; c[3] = (_Float16)x0.w;
                c[4] = (_Float16)x1.x; c[5] = (_Float16)x1.y; c[6] = (_Float16)x1.z; c[7] = (_Float16)x1.w;
                bx[ng][ks] = c;
            } else {
                bx[ng][ks] = (half8_t)(_Float16)0.0f;
            }
        }
    }

    const half_t* Ws[3] = {Wq, Wk, Wv};
    const float*  Bs[3] = {bq, bk, bv};

    #pragma unroll
    for (int o = 0; o < 3; ++o) {
        const half_t* W = Ws[o];
        #pragma unroll
        for (int ct = 0; ct < 8; ++ct) {
            f32x4 acc0 = {0.f, 0.f, 0.f, 0.f};
            f32x4 acc1 = {0.f, 0.f, 0.f, 0.f};
            #pragma unroll
            for (int ks = 0; ks < 4; ++ks) {
                const half8_t a = *(const half8_t*)(W + (size_t)(ct * 16 + cl) * DIM + ks * 32 + kg * 8);
                acc0 = __builtin_amdgcn_mfma_f32_16x16x32_f16(a, bx[0][ks], acc0, 0, 0, 0);
                acc1 = __builtin_amdgcn_mfma_f32_16x16x32_f16(a, bx[1][ks], acc1, 0, 0, 0);
            }
            const int c0 = ct * 16 + kg * 4;            // this lane's 4 consecutive outcols
            const float4 b4 = *(const float4*)(Bs[o] + c0);
            const float v00 = acc0[0] + b4.x, v01 = acc0[1] + b4.y,
                        v02 = acc0[2] + b4.z, v03 = acc0[3] + b4.w;
            const float v10 = acc1[0] + b4.x, v11 = acc1[1] + b4.y,
                        v12 = acc1[2] + b4.z, v13 = acc1[3] + b4.w;
            const int n0 = m0 + cl;
            const int n1 = m0 + 16 + cl;
            if (o == 1) {   // K -> fp8
                if (n0 < N_NODES) {
                    int pk = __builtin_amdgcn_cvt_pk_fp8_f32(v00, v01, 0, false);
                    pk = __builtin_amdgcn_cvt_pk_fp8_f32(v02, v03, pk, true);
                    *(u32*)(K8 + (size_t)n0 * DIM + c0) = (u32)pk;
                }
                if (n1 < N_NODES) {
                    int pk = __builtin_amdgcn_cvt_pk_fp8_f32(v10, v11, 0, false);
                    pk = __builtin_amdgcn_cvt_pk_fp8_f32(v12, v13, pk, true);
                    *(u32*)(K8 + (size_t)n1 * DIM + c0) = (u32)pk;
                }
            } else {
                half_t* O = (o == 0) ? Qo : Vo;
                if (n0 < N_NODES) {
                    half4_t hd4;
                    hd4[0] = (_Float16)v00; hd4[1] = (_Float16)v01;
                    hd4[2] = (_Float16)v02; hd4[3] = (_Float16)v03;
                    *(half4_t*)(O + (size_t)n0 * DIM + c0) = hd4;
                }
                if (n1 < N_NODES) {
                    half4_t hd4;
                    hd4[0] = (_Float16)v10; hd4[1] = (_Float16)v11;
                    hd4[2] = (_Float16)v12; hd4[3] = (_Float16)v13;
                    *(half4_t*)(O + (size_t)n1 * DIM + c0) = hd4;
                }
            }
        }
    }
}

// ---------------- B4: per-bucket CSR finalize: offs + srcs (LDS atomics only) ----------------
__global__ __launch_bounds__(256)
void csr_build(const u32* __restrict__ BE, const int* __restrict__ gbase,
               int* __restrict__ offs, int* __restrict__ srcs)
{
    __shared__ int dcnt[128], dof[128], dcur[128];
    const int b   = blockIdx.x;
    const int tid = threadIdx.x;
    const int t0  = b << 7;
    const int nt  = (N_NODES - t0) < 128 ? (N_NODES - t0) : 128;
    const int base = gbase[b];
    const int end  = gbase[b + 1];
    if (tid < 128) dcnt[tid] = 0;
    __syncthreads();
    for (int k = base + tid; k < end; k += 256)
        atomicAdd(&dcnt[(int)(BE[k] >> 16) - t0], 1);
    __syncthreads();
    if (tid < 128) dof[tid] = dcnt[tid];
    __syncthreads();
    for (int s = 1; s < 128; s <<= 1) {
        int a = 0;
        if (tid < 128 && tid >= s) a = dof[tid - s];
        __syncthreads();
        if (tid < 128) dof[tid] += a;
        __syncthreads();
    }
    if (tid < 128) {
        const int ex = dof[tid] - dcnt[tid];
        dof[tid] = ex;
        dcur[tid] = 0;
        if (tid < nt) offs[t0 + tid] = base + ex;
    }
    __syncthreads();
    for (int k = base + tid; k < end; k += 256) {
        const u32 ev = BE[k];
        const int tl = (int)(ev >> 16) - t0;
        const int p  = atomicAdd(&dcur[tl], 1);
        srcs[base + dof[tl] + p] = (int)(ev & 0xFFFFu);
    }
}

// ---------------- output GEMM + bias + residual + LayerNorm, transposed output ----------------
__global__ __launch_bounds__(256)
void out_mfma_ln(const half_t* __restrict__ Ah, const half_t* __restrict__ Wo,
                 const float* __restrict__ bo, const float* __restrict__ X,
                 const float* __restrict__ lng, const float* __restrict__ lnb,
                 float* __restrict__ out)
{
    const int lane = threadIdx.x & 63;
    const int wv   = threadIdx.x >> 6;
    const int m0   = blockIdx.x * 128 + wv * 32;
    const int cl   = lane & 15;
    const int kg   = lane >> 4;

    half8_t bx[2][4];
    #pragma unroll
    for (int ng = 0; ng < 2; ++ng) {
        const int row = m0 + ng * 16 + cl;
        #pragma unroll
        for (int ks = 0; ks < 4; ++ks) {
            if (row < N_NODES)
                bx[ng][ks] = *(const half8_t*)(Ah + (size_t)row * DIM + ks * 32 + kg * 8);
            else
                bx[ng][ks] = (half8_t)(_Float16)0.0f;
        }
    }

    float y[2][8][4];
    #pragma unroll
    for (int ct = 0; ct < 8; ++ct) {
        f32x4 acc0 = {0.f, 0.f, 0.f, 0.f};
        f32x4 acc1 = {0.f, 0.f, 0.f, 0.f};
        #pragma unroll
        for (int ks = 0; ks < 4; ++ks) {
            const half8_t a = *(const half8_t*)(Wo + (size_t)(ct * 16 + cl) * DIM + ks * 32 + kg * 8);
            acc0 = __builtin_amdgcn_mfma_f32_16x16x32_f16(a, bx[0][ks], acc0, 0, 0, 0);
            acc1 = __builtin_amdgcn_mfma_f32_16x16x32_f16(a, bx[1][ks], acc1, 0, 0, 0);
        }
        const int c0 = ct * 16 + kg * 4;
        const float4 b4 = *(const float4*)(bo + c0);
        const int n0 = m0 + cl;
        const int n1 = m0 + 16 + cl;
        float4 x0 = make_float4(0.f, 0.f, 0.f, 0.f), x1 = x0;
        if (n0 < N_NODES) x0 = *(const float4*)(X + (size_t)n0 * DIM + c0);
        if (n1 < N_NODES) x1 = *(const float4*)(X + (size_t)n1 * DIM + c0);
        y[0][ct][0] = acc0[0] + b4.x + x0.x; y[0][ct][1] = acc0[1] + b4.y + x0.y;
        y[0][ct][2] = acc0[2] + b4.z + x0.z; y[0][ct][3] = acc0[3] + b4.w + x0.w;
        y[1][ct][0] = acc1[0] + b4.x + x1.x; y[1][ct][1] = acc1[1] + b4.y + x1.y;
        y[1][ct][2] = acc1[2] + b4.z + x1.z; y[1][ct][3] = acc1[3] + b4.w + x1.w;
    }

    #pragma unroll
    for (int ng = 0; ng < 2; ++ng) {
        float s = 0.f, sq = 0.f;
        #pragma unroll
        for (int ct = 0; ct < 8; ++ct)
            #pragma unroll
            for (int j = 0; j < 4; ++j) { const float v = y[ng][ct][j]; s += v; sq += v * v; }
        s += __shfl_xor(s, 16); sq += __shfl_xor(sq, 16);
        s += __shfl_xor(s, 32); sq += __shfl_xor(sq, 32);
        const float mu   = s * (1.0f / 128.0f);
        const float var  = sq * (1.0f / 128.0f) - mu * mu;
        const float rstd = rsqrtf(var + 1e-5f);
        const int node = m0 + ng * 16 + cl;
        if (node < N_NODES) {
            #pragma unroll
            for (int ct = 0; ct < 8; ++ct) {
                const int c0 = ct * 16 + kg * 4;
                const float4 g4 = *(const float4*)(lng + c0);
                const float4 l4 = *(const float4*)(lnb + c0);
                float4 ov;
                ov.x = g4.x * (y[ng][ct][0] - mu) * rstd + l4.x;
                ov.y = g4.y * (y[ng][ct][1] - mu) * rstd + l4.y;
                ov.z = g4.z * (y[ng][ct][2] - mu) * rstd + l4.z;
                ov.w = g4.w * (y[ng][ct][3] - mu) * rstd + l4.w;
                *(float4*)(out + (size_t)node * DIM + c0) = ov;
            }
        }
    }
}

// ---------------- per-node attention + aggregation (1 wave / node, fp8 K, fp16 V) ----------
// Score layout: lane = 4*jl + h (16 edges x 4 heads); K fp8 head slice = 32B = 2 x uint4.
// V layout: lane owns dims d16*8..+7 (16B half8 loads, 4 passes x 4 edges); packed half2
// accumulation; cross-group combine via shfl_xor(16,32) at the end.
__global__ __launch_bounds__(256)
void attn_agg(const half_t* __restrict__ Qh, const u8* __restrict__ K8,
              const half_t* __restrict__ Vh, const int* __restrict__ offs,
              const int* __restrict__ srcs, half_t* __restrict__ AGG)
{
    const int lane = threadIdx.x & 63;
    const int t = blockIdx.x * 4 + (threadIdx.x >> 6);
    if (t >= N_NODES) return;
    const int off = offs[t];
    const int deg = offs[t + 1] - off;
    const int h   = lane & 3;
    const int jl  = lane >> 2;
    const int d16 = lane & 15;          // V dim-chunk (8 halves = 16B)
    const int hv  = d16 >> 2;           // head owning dims d16*8..+7
    const int jv  = lane >> 4;          // edge offset within a V pass

    f32x2 q2[16];   // dims (2j, 2j+1) of this lane's head slice, f32
    {
        const half_t* qp = Qh + (size_t)t * DIM + h * DH;
        #pragma unroll
        for (int i = 0; i < 4; ++i) {
            const half8_t v8 = *(const half8_t*)(qp + i * 8);
            #pragma unroll
            for (int p = 0; p < 4; ++p) {
                f32x2 qv; qv[0] = (float)v8[2*p]; qv[1] = (float)v8[2*p+1];
                q2[i * 4 + p] = qv;
            }
        }
    }

    float ssumL = 0.f;                       // per-lane (score layout)
    half2_t acc[4];                          // packed accum for dims d16*8..+7
    #pragma unroll
    for (int q = 0; q < 4; ++q) acc[q] = (half2_t)(_Float16)0.0f;
    const int nch = (deg + 15) >> 4;

    int sA = 0;
    u32 kA[8] = {};
    {
        const int cnt0 = deg < 16 ? deg : 16;
        if (jl < cnt0) {
            sA = srcs[off + jl];
            const u32* kp = (const u32*)(K8 + (size_t)sA * DIM + h * DH);
            const uint4 ka = *(const uint4*)(kp);
            const uint4 kb = *(const uint4*)(kp + 4);
            kA[0] = ka.x; kA[1] = ka.y; kA[2] = ka.z; kA[3] = ka.w;
            kA[4] = kb.x; kA[5] = kb.y; kA[6] = kb.z; kA[7] = kb.w;
        }
    }

    for (int c = 0; c < nch; ++c) {
        const int base = c << 4;
        const int cnt = (deg - base) < 16 ? (deg - base) : 16;

        // prefetch next chunk's srcs + K
        int sB = 0;
        u32 kB[8] = {};
        if (c + 1 < nch) {
            const int rem = deg - base - 16;
            const int cntn = rem < 16 ? rem : 16;
            if (jl < cntn) {
                sB = srcs[off + base + 16 + jl];
                const u32* kp = (const u32*)(K8 + (size_t)sB * DIM + h * DH);
                const uint4 ka = *(const uint4*)(kp);
                const uint4 kb = *(const uint4*)(kp + 4);
                kB[0] = ka.x; kB[1] = ka.y; kB[2] = ka.z; kB[3] = ka.w;
                kB[4] = kb.x; kB[5] = kb.y; kB[6] = kb.z; kB[7] = kb.w;
            }
        }

        // score: unpack fp8 -> f32 pairs, packed fma against q
        f32x2 dq2 = {0.f, 0.f};
        #pragma unroll
        for (int p = 0; p < 8; ++p) {
            const f32x2 lo = __builtin_amdgcn_cvt_pk_f32_fp8((int)kA[p], false);
            const f32x2 hi = __builtin_amdgcn_cvt_pk_f32_fp8((int)kA[p], true);
            dq2 = lo * q2[2*p]   + dq2;
            dq2 = hi * q2[2*p+1] + dq2;
        }
        const float dq = dq2[0] + dq2[1];
        const float e = (jl < cnt) ? __expf(dq * SCALEF) : 0.f;
        ssumL += e;

        // packed (e,e) for broadcast
        union { u32 u; half2_t h2; } pe;
        const _Float16 eh = (_Float16)e;
        pe.h2[0] = eh; pe.h2[1] = eh;
        const int peI = (int)pe.u;

        // V aggregation: 4 passes x 4 edges; one 16B load per lane per pass
        #pragma unroll
        for (int p = 0; p < 4; ++p) {
            const int j  = p * 4 + jv;
            const int sj = __shfl(sA, j * 4);
            union { u32 u; half2_t h2; } e2;
            e2.u = (u32)__shfl(peI, j * 4 + hv);
            union { half8_t v8; half2_t h2[4]; } v;
            v.v8 = *(const half8_t*)(Vh + (size_t)sj * DIM + d16 * 8);
            acc[0] = e2.h2 * v.h2[0] + acc[0];
            acc[1] = e2.h2 * v.h2[1] + acc[1];
            acc[2] = e2.h2 * v.h2[2] + acc[2];
            acc[3] = e2.h2 * v.h2[3] + acc[3];
        }

        sA = sB;
        #pragma unroll
        for (int p = 0; p < 8; ++p) kA[p] = kB[p];
    }

    // combine the 4 edge groups (lanes l, l^16, l^32, l^48 hold the same dims)
    #pragma unroll
    for (int q = 0; q < 4; ++q) {
        union { u32 u; half2_t h2; } cq, dq16, dq32;
        cq.h2 = acc[q];
        dq16.u = (u32)__shfl_xor((int)cq.u, 16);
        cq.h2 = cq.h2 + dq16.h2;
        dq32.u = (u32)__shfl_xor((int)cq.u, 32);
        acc[q] = cq.h2 + dq32.h2;
    }

    // denominator: reduce ssumL over bits 2..5 (lanes sharing h); head-hv sum lives in lane hv
    float se = ssumL;
    #pragma unroll
    for (int ww = 4; ww < 64; ww <<= 1) se += __shfl_xor(se, ww);
    const float sh = __shfl(se, hv);
    const float inv = 1.0f / (sh + 1e-10f);

    if (lane < 16) {
        half8_t o;
        #pragma unroll
        for (int q = 0; q < 4; ++q) {
            o[2*q]   = (_Float16)((float)acc[q][0] * inv);
            o[2*q+1] = (_Float16)((float)acc[q][1] * inv);
        }
        *(half8_t*)(AGG + (size_t)t * DIM + d16 * 8) = o;
    }
}

extern "C" void kernel_launch(void* const* d_in, const int* in_sizes, int n_in,
                              void* d_out, int out_size, void* d_ws, size_t ws_size,
                              hipStream_t stream)
{
    const float* X   = (const float*)d_in[0];
    const float* Wq  = (const float*)d_in[1];
    const float* bq  = (const float*)d_in[2];
    const float* Wk  = (const float*)d_in[3];
    const float* bk  = (const float*)d_in[4];
    const float* Wv  = (const float*)d_in[5];
    const float* bv  = (const float*)d_in[6];
    const float* Wo  = (const float*)d_in[7];
    const float* bo  = (const float*)d_in[8];
    const float* lng = (const float*)d_in[9];
    const float* lnb = (const float*)d_in[10];
    const int*   ei  = (const int*)d_in[11];
    float* out = (float*)d_out;

    const size_t ND = (size_t)N_NODES * DIM;   // 6.4M elems
    half_t* Qh   = (half_t*)d_ws;
    half_t* Vh   = Qh + ND;
    half_t* AGGh = Vh + ND;
    half_t* Wqh  = AGGh + ND;
    half_t* Wkh  = Wqh + DIM * DIM;
    half_t* Wvh  = Wkh + DIM * DIM;
    half_t* Woh  = Wvh + DIM * DIM;
    u8* K8    = (u8*)(Woh + DIM * DIM);
    u32* BE   = (u32*)(K8 + ND);
    int* OFFS = (int*)(BE + NE);
    int* SRCS = OFFS + N_NODES + 1;
    int* GCNT = SRCS + NE;
    int* GBASE = GCNT + 512;
    int* GCUR  = GBASE + 512;

    hipMemsetAsync(GCNT, 0, 512 * sizeof(int), stream);

    // weights -> fp16 + bucket histogram (one launch)
    prep_kernel<<<32 + EB, 256, 0, stream>>>(Wq, Wk, Wv, Wo, Wqh, Wkh, Wvh, Woh,
                                             ei + NE, GCNT);

    // bucket scan -> base/cursor
    bucket_scan<<<1, 512, 0, stream>>>(GCNT, GBASE, GCUR, OFFS);

    // bucket scatter + QKV projections (one launch; independent block ranges)
    const int gemmGrid = (N_NODES + 127) / 128;   // 391
    scat_qkv<<<EB + gemmGrid, 256, 0, stream>>>(ei, GCUR, BE,
                                                X, Wqh, Wkh, Wvh, bq, bk, bv,
                                                Qh, K8, Vh);

    // per-bucket CSR finalize (LDS atomics only)
    csr_build<<<NBKT, 256, 0, stream>>>(BE, GBASE, OFFS, SRCS);

    // attention + aggregation
    attn_agg<<<(N_NODES + 3) / 4, 256, 0, stream>>>(Qh, K8, Vh, OFFS, SRCS, AGGh);

    // output projection + residual + LayerNorm
    out_mfma_ln<<<gemmGrid, 256, 0, stream>>>(AGGh, Woh, bo, X, lng, lnb, out);
}